// Round 4
// baseline (1978.186 us; speedup 1.0000x reference)
//
#include <hip/hip_runtime.h>
#include <hip/hip_bf16.h>

// ---------------------------------------------------------------------------
// PUSCH neural detector: 4 stacked ConvLSTM layers on [B=2,T=14,H=1536,W=1].
// W-dim of the conv is size 1 -> 3x3 conv degenerates to 1-D width-3 conv
// along H using the kw=1 kernel slice (jax conv = cross-correlation).
// Inputs f32, OUTPUT f32 (reference returns float32), compute f32.
// ---------------------------------------------------------------------------

#define BB   2
#define TT   14
#define LL   1536
#define CINR 297      // real input channels
#define CINP 304      // padded to multiple of 16 for GEMM chunking

// ---- workspace layout (units: f32 elements) -------------------------------
static constexpr size_t SZ_WXIN  = (size_t)3*CINP*256;   // 233472 (padded)
static constexpr size_t SZ_WH64  = (size_t)3*64*256;     // 49152
static constexpr size_t SZ_WXOUT = (size_t)3*64*128;     // 24576
static constexpr size_t SZ_WHOUT = (size_t)3*32*128;     // 12288

static constexpr size_t OFF_WXIN  = 0;
static constexpr size_t OFF_WHIN  = OFF_WXIN  + SZ_WXIN;
static constexpr size_t OFF_WXR0  = OFF_WHIN  + SZ_WH64;
static constexpr size_t OFF_WHR0  = OFF_WXR0  + SZ_WH64;
static constexpr size_t OFF_WXR1  = OFF_WHR0  + SZ_WH64;
static constexpr size_t OFF_WHR1  = OFF_WXR1  + SZ_WH64;
static constexpr size_t OFF_WXOUT = OFF_WHR1  + SZ_WH64;
static constexpr size_t OFF_WHOUT = OFF_WXOUT + SZ_WXOUT;
static constexpr size_t OFF_BIN   = OFF_WHOUT + SZ_WHOUT;
static constexpr size_t OFF_BR0   = OFF_BIN + 256;
static constexpr size_t OFF_BR1   = OFF_BR0 + 256;
static constexpr size_t OFF_BOUT  = OFF_BR1 + 256;
static constexpr size_t PREP_TOTAL = OFF_BOUT + 128;     // 516992 elements

static constexpr size_t OFF_Z0  = 524288;                 // f32 [28][1536][304]
static constexpr size_t SZ_Z0   = (size_t)BB*TT*LL*CINP;  // 13074432
static constexpr size_t OFF_XZ  = OFF_Z0 + SZ_Z0;         // f32 [28][1536][256]
static constexpr size_t SZ_XZ   = (size_t)BB*TT*LL*256;   // 11010048
static constexpr size_t OFF_SEQ = OFF_XZ + SZ_XZ;         // f32 [28][1536][64]
static constexpr size_t SZ_SEQ  = (size_t)BB*TT*LL*64;    // 2752512
static constexpr size_t OFF_HA  = OFF_SEQ + SZ_SEQ;       // h state dbuf
static constexpr size_t SZ_HST  = (size_t)BB*LL*64;       // 196608
static constexpr size_t OFF_HB  = OFF_HA + SZ_HST;
static constexpr size_t OFF_CS  = OFF_HB + SZ_HST;        // c state
// total end = 27,951,104 f32 = ~112 MB

__device__ __forceinline__ float hsig(float x) {
    return fminf(fmaxf(0.2f * x + 0.5f, 0.0f), 1.0f);
}

// ---------------------------------------------------------------------------
// prep_weights: extract kw=1 slice of every 3x3 kernel.
// Wx stored [k][ci][co] (ci padded for layer-in). Wh stored transposed
// [k][ci][f][gate4] so the step kernel reads the 4 gate weights as float4.
// ---------------------------------------------------------------------------
__device__ __forceinline__ float wx_mid(const float* src, int Cin, int N, int idx) {
    int k = idx / (Cin * N); int r = idx - k * (Cin * N);
    int ci = r / N; int co = r - ci * N;
    return src[((size_t)(k * 3 + 1) * Cin + ci) * N + co];
}
__device__ __forceinline__ float wh_midT(const float* src, int F_, int idx) {
    int N4 = 4 * F_;
    int k = idx / (F_ * N4); int r = idx - k * (F_ * N4);
    int ci = r / N4; int fg = r - ci * N4;
    int f = fg >> 2, g = fg & 3;
    return src[((size_t)(k * 3 + 1) * F_ + ci) * N4 + g * F_ + f];
}

__global__ __launch_bounds__(256)
void prep_weights_kernel(const float* wx_in, const float* wh_in, const float* b_in,
                         const float* wx_r0, const float* wh_r0, const float* b_r0,
                         const float* wx_r1, const float* wh_r1, const float* b_r1,
                         const float* wx_out, const float* wh_out, const float* b_out,
                         float* __restrict__ ws)
{
    int idx = blockIdx.x * 256 + threadIdx.x;
    if (idx < (int)SZ_WXIN) {                      // Wx_in, padded 297 -> 304
        int k = idx / (CINP * 256); int r = idx - k * (CINP * 256);
        int ci = r >> 8; int co = r & 255;
        float v = 0.0f;
        if (ci < CINR) v = wx_in[((size_t)(k * 3 + 1) * CINR + ci) * 256 + co];
        ws[OFF_WXIN + idx] = v; return;
    }
    idx -= (int)SZ_WXIN;
    if (idx < (int)SZ_WH64) { ws[OFF_WHIN + idx] = wh_midT(wh_in, 64, idx); return; }
    idx -= (int)SZ_WH64;
    if (idx < (int)SZ_WH64) { ws[OFF_WXR0 + idx] = wx_mid(wx_r0, 64, 256, idx); return; }
    idx -= (int)SZ_WH64;
    if (idx < (int)SZ_WH64) { ws[OFF_WHR0 + idx] = wh_midT(wh_r0, 64, idx); return; }
    idx -= (int)SZ_WH64;
    if (idx < (int)SZ_WH64) { ws[OFF_WXR1 + idx] = wx_mid(wx_r1, 64, 256, idx); return; }
    idx -= (int)SZ_WH64;
    if (idx < (int)SZ_WH64) { ws[OFF_WHR1 + idx] = wh_midT(wh_r1, 64, idx); return; }
    idx -= (int)SZ_WH64;
    if (idx < (int)SZ_WXOUT) { ws[OFF_WXOUT + idx] = wx_mid(wx_out, 64, 128, idx); return; }
    idx -= (int)SZ_WXOUT;
    if (idx < (int)SZ_WHOUT) { ws[OFF_WHOUT + idx] = wh_midT(wh_out, 32, idx); return; }
    idx -= (int)SZ_WHOUT;
    if (idx < 256) { ws[OFF_BIN + idx] = b_in[idx];  return; }
    idx -= 256;
    if (idx < 256) { ws[OFF_BR0 + idx] = b_r0[idx];  return; }
    idx -= 256;
    if (idx < 256) { ws[OFF_BR1 + idx] = b_r1[idx];  return; }
    idx -= 256;
    if (idx < 128) { ws[OFF_BOUT + idx] = b_out[idx]; return; }
}

// ---------------------------------------------------------------------------
// build_features: gather [y | h | err | no] -> z0 f32 [28][1536][304]
// ---------------------------------------------------------------------------
__global__ __launch_bounds__(256)
void build_features_kernel(const float* __restrict__ y,
                           const float* __restrict__ h,
                           const float* __restrict__ ev,
                           const float* __restrict__ no,
                           float* __restrict__ z0)
{
    long long idx = (long long)blockIdx.x * 256 + threadIdx.x;
    const long long total = (long long)BB * TT * LL * CINP;
    if (idx >= total) return;
    int c = (int)(idx % CINP);
    long long rest = idx / CINP;
    int l = (int)(rest % LL); rest /= LL;
    int t = (int)(rest % TT);
    int b = (int)(rest / TT);
    float v = 0.0f;
    if (c < 32) {                                   // y_ri: (b,1,16,T,L,2), c=na*2+ri
        int na = c >> 1, ri = c & 1;
        v = y[((((long long)b * 16 + na) * TT + t) * LL + l) * 2 + ri];
    } else if (c < 288) {                           // h_ri: c-32 = na*16+ue*4+spu*2+ri
        int q = c - 32;
        int ri = q & 1, nspu = (q >> 1) & 1, nue = (q >> 2) & 3, na = q >> 4;
        v = h[((((((long long)b * 16 + na) * 4 + nue) * 2 + nspu) * TT + t) * LL + l) * 2 + ri];
    } else if (c < 296) {                           // err_var: (ue,spu,T,L), c-288 = ue*2+spu
        int q = c - 288; int nspu = q & 1, nue = q >> 1;
        v = ev[(((long long)(nue * 2 + nspu) * TT + t) * LL) + l];
    } else if (c == 296) {
        v = no[0];
    }
    z0[idx] = v;
}

// ---------------------------------------------------------------------------
// xz_gemm: out[bt][l][co] = bias[co] + sum_{kh,ci} A[bt][l+kh-1][ci]*W[kh][ci][co]
// 128x128 tile, 8x8 per thread, A tile staged with conv halo (+1 row each side).
// ---------------------------------------------------------------------------
__global__ __launch_bounds__(256)
void xz_gemm_kernel(const float* __restrict__ A, int CinPitch,
                    const float* __restrict__ Wg, const float* __restrict__ bias,
                    float* __restrict__ out, int Ncol)
{
    __shared__ float As[130 * 17];
    __shared__ float Ws[3 * 16 * 128];
    const int tid = threadIdx.x;
    const int bt = blockIdx.y;
    const int l0 = blockIdx.x * 128;
    const int n0 = blockIdx.z * 128;
    const int mbase = (tid >> 4) * 8;
    const int nbase = (tid & 15) * 8;

    float acc[8][8];
#pragma unroll
    for (int i = 0; i < 8; i++)
#pragma unroll
        for (int j = 0; j < 8; j++) acc[i][j] = 0.0f;

    for (int cc0 = 0; cc0 < CinPitch; cc0 += 16) {
        __syncthreads();
        // stage A rows l0-1 .. l0+128 (zero outside image), 16 channels
        for (int idx = tid; idx < 130 * 16; idx += 256) {
            int r = idx >> 4, c = idx & 15;
            int row = l0 + r - 1;
            float v = 0.0f;
            if (row >= 0 && row < LL)
                v = A[((size_t)bt * LL + row) * CinPitch + cc0 + c];
            As[r * 17 + c] = v;
        }
        // stage W: [3][16][128]
        for (int idx = tid; idx < 3 * 16 * 128; idx += 256) {
            int kh = idx >> 11;
            int r2 = idx & 2047;
            int kk = r2 >> 7, n = r2 & 127;
            Ws[idx] = Wg[((size_t)kh * CinPitch + cc0 + kk) * Ncol + n0 + n];
        }
        __syncthreads();
        for (int kk = 0; kk < 16; ++kk) {
#pragma unroll
            for (int kh = 0; kh < 3; ++kh) {
                float a[8], w[8];
#pragma unroll
                for (int i = 0; i < 8; i++) a[i] = As[(mbase + i + kh) * 17 + kk];
                const float* wrow = &Ws[(kh * 16 + kk) * 128 + nbase];
#pragma unroll
                for (int j = 0; j < 8; j++) w[j] = wrow[j];
#pragma unroll
                for (int i = 0; i < 8; i++)
#pragma unroll
                    for (int j = 0; j < 8; j++)
                        acc[i][j] = fmaf(a[i], w[j], acc[i][j]);
            }
        }
    }
#pragma unroll
    for (int i = 0; i < 8; i++) {
        int row = l0 + mbase + i;
        float* orow = out + ((size_t)bt * LL + row) * Ncol + n0 + nbase;
#pragma unroll
        for (int j = 0; j < 8; j++) orow[j] = acc[i][j] + bias[n0 + nbase + j];
    }
}

// ---------------------------------------------------------------------------
// lstm_step: one timestep. z = xz[t] + conv3(h_prev, Wh); gates; update c,h.
// h state double-buffered across launches (halo reads would race otherwise).
// seq is read (residual) and written IN PLACE at the same index by the same
// thread -> no race; deliberately NOT __restrict__.
// ---------------------------------------------------------------------------
template <int F_, bool RESID, bool OUTW>
__global__ __launch_bounds__(256)
void lstm_step_kernel(const float* __restrict__ xz,      // [28][1536][4F_] (bias incl)
                      const float* __restrict__ Whet,    // [3][F_][F_][4]
                      const float* __restrict__ hprev,   // [B][1536][F_]
                      float* __restrict__ hnext,
                      float* __restrict__ cstate,
                      float* seq,                        // layer in/out seq (or null)
                      float* __restrict__ dout,          // final output f32 (or null)
                      int t)
{
    constexpr int ROWS = 16;
    constexpr int RG = 256 / F_;        // row groups per block: 4 (F=64) / 8 (F=32)
    constexpr int R = ROWS / RG;        // rows per thread:      4 / 2
    __shared__ float Hs[(ROWS + 2) * F_];
    __shared__ float Ws[16 * F_ * 4];

    const int tid = threadIdx.x;
    const int f = tid % F_;
    const int rg = tid / F_;
    const int nLb = LL / ROWS;          // 96
    const int b = blockIdx.x / nLb;
    const int l0 = (blockIdx.x % nLb) * ROWS;
    const int rgR = rg * R;

    // stage h_prev rows l0-1 .. l0+16 (zeros at t==0 / image edges)
    for (int idx = tid; idx < (ROWS + 2) * F_; idx += 256) {
        int r = idx / F_, c = idx % F_;
        int row = l0 + r - 1;
        float v = 0.0f;
        if (t > 0 && row >= 0 && row < LL) v = hprev[((size_t)b * LL + row) * F_ + c];
        Hs[idx] = v;
    }

    float zh[R][4];
#pragma unroll
    for (int i = 0; i < R; i++) { zh[i][0] = zh[i][1] = zh[i][2] = zh[i][3] = 0.0f; }

    constexpr int KC = 3 * F_;
    for (int kc0 = 0; kc0 < KC; kc0 += 16) {
        __syncthreads();            // protects prev Ws reads (and first-iter Hs)
        for (int idx = tid; idx < 16 * F_ * 4; idx += 256)
            Ws[idx] = Whet[(size_t)kc0 * F_ * 4 + idx];
        __syncthreads();
        const int k = kc0 / F_;     // constant within chunk (16 | F_)
        const int ci0 = kc0 - k * F_;
#pragma unroll 4
        for (int j = 0; j < 16; j++) {
            int ci = ci0 + j;
            const float4 w4 = *reinterpret_cast<const float4*>(&Ws[(j * F_ + f) * 4]);
#pragma unroll
            for (int i = 0; i < R; i++) {
                float hv = Hs[(rgR + i + k) * F_ + ci];   // wave-uniform addr -> broadcast
                zh[i][0] = fmaf(hv, w4.x, zh[i][0]);
                zh[i][1] = fmaf(hv, w4.y, zh[i][1]);
                zh[i][2] = fmaf(hv, w4.z, zh[i][2]);
                zh[i][3] = fmaf(hv, w4.w, zh[i][3]);
            }
        }
    }

    const size_t btL = ((size_t)b * TT + t) * LL;
#pragma unroll
    for (int i = 0; i < R; i++) {
        int l = l0 + rgR + i;
        size_t rowoff = (btL + l) * (size_t)(4 * F_);
        float zi = xz[rowoff + 0 * F_ + f] + zh[i][0];
        float zf = xz[rowoff + 1 * F_ + f] + zh[i][1];
        float zg = xz[rowoff + 2 * F_ + f] + zh[i][2];
        float zo = xz[rowoff + 3 * F_ + f] + zh[i][3];
        float ig = hsig(zi), fg = hsig(zf);
        float gg = tanhf(zg), og = hsig(zo);
        size_t soff = ((size_t)b * LL + l) * F_ + f;
        float cp = (t > 0) ? cstate[soff] : 0.0f;
        float cn = fg * cp + ig * gg;
        float hn = og * tanhf(cn);
        cstate[soff] = cn;
        hnext[soff] = hn;
        if (OUTW) {
            // out[b][ue][spu][n*4+bit]; f = ue*8 + spu*4 + bit; n = t*L + l
            int ue = f >> 3, spu = (f >> 2) & 1, bit = f & 3;
            size_t n = (size_t)t * LL + l;
            dout[(((size_t)b * 4 + ue) * 2 + spu) * ((size_t)TT * LL * 4) + n * 4 + bit] = hn;
        } else {
            float v = hn;
            if (RESID) v += seq[(btL + l) * F_ + f];   // read-then-write same idx
            seq[(btL + l) * F_ + f] = v;
        }
    }
}

// ---------------------------------------------------------------------------
extern "C" void kernel_launch(void* const* d_in, const int* in_sizes, int n_in,
                              void* d_out, int out_size, void* d_ws, size_t ws_size,
                              hipStream_t stream)
{
    (void)in_sizes; (void)n_in; (void)out_size; (void)ws_size;
    const float* y_ri   = (const float*)d_in[0];
    const float* h_ri   = (const float*)d_in[1];
    const float* evar   = (const float*)d_in[2];
    const float* no     = (const float*)d_in[3];
    const float* wx_in  = (const float*)d_in[4];
    const float* wh_in  = (const float*)d_in[5];
    const float* b_in   = (const float*)d_in[6];
    const float* wx_r0  = (const float*)d_in[7];
    const float* wh_r0  = (const float*)d_in[8];
    const float* b_r0   = (const float*)d_in[9];
    const float* wx_r1  = (const float*)d_in[10];
    const float* wh_r1  = (const float*)d_in[11];
    const float* b_r1   = (const float*)d_in[12];
    const float* wx_out = (const float*)d_in[13];
    const float* wh_out = (const float*)d_in[14];
    const float* b_out  = (const float*)d_in[15];

    float* ws = (float*)d_ws;
    float* dout = (float*)d_out;          // reference output dtype is float32

    // 1) weights -> effective 1-D kernels
    {
        int blocks = (int)((PREP_TOTAL + 255) / 256);
        prep_weights_kernel<<<blocks, 256, 0, stream>>>(
            wx_in, wh_in, b_in, wx_r0, wh_r0, b_r0,
            wx_r1, wh_r1, b_r1, wx_out, wh_out, b_out, ws);
    }
    // 2) feature assembly -> z0 f32 [28][1536][304]
    {
        long long total = (long long)BB * TT * LL * CINP;
        int blocks = (int)((total + 255) / 256);
        build_features_kernel<<<blocks, 256, 0, stream>>>(
            y_ri, h_ri, evar, no, ws + OFF_Z0);
    }

    float* hA = ws + OFF_HA;
    float* hB = ws + OFF_HB;
    float* cs = ws + OFF_CS;
    float* seq = ws + OFF_SEQ;
    const dim3 g256(12, BB * TT, 2);   // Ncol=256
    const dim3 g128(12, BB * TT, 1);   // Ncol=128

    // ---- layer in: Cin=297(p304) -> F=64, writes seq
    xz_gemm_kernel<<<g256, 256, 0, stream>>>(
        ws + OFF_Z0, CINP, ws + OFF_WXIN, ws + OFF_BIN, ws + OFF_XZ, 256);
    for (int t = 0; t < TT; t++)
        lstm_step_kernel<64, false, false><<<BB * (LL / 16), 256, 0, stream>>>(
            ws + OFF_XZ, ws + OFF_WHIN, (t & 1) ? hB : hA, (t & 1) ? hA : hB, cs,
            seq, nullptr, t);

    // ---- layer r0 (+residual, in-place on seq)
    xz_gemm_kernel<<<g256, 256, 0, stream>>>(
        seq, 64, ws + OFF_WXR0, ws + OFF_BR0, ws + OFF_XZ, 256);
    for (int t = 0; t < TT; t++)
        lstm_step_kernel<64, true, false><<<BB * (LL / 16), 256, 0, stream>>>(
            ws + OFF_XZ, ws + OFF_WHR0, (t & 1) ? hB : hA, (t & 1) ? hA : hB, cs,
            seq, nullptr, t);

    // ---- layer r1 (+residual, in-place on seq)
    xz_gemm_kernel<<<g256, 256, 0, stream>>>(
        seq, 64, ws + OFF_WXR1, ws + OFF_BR1, ws + OFF_XZ, 256);
    for (int t = 0; t < TT; t++)
        lstm_step_kernel<64, true, false><<<BB * (LL / 16), 256, 0, stream>>>(
            ws + OFF_XZ, ws + OFF_WHR1, (t & 1) ? hB : hA, (t & 1) ? hA : hB, cs,
            seq, nullptr, t);

    // ---- layer out: F=32, writes d_out (f32, transposed layout)
    xz_gemm_kernel<<<g128, 256, 0, stream>>>(
        seq, 64, ws + OFF_WXOUT, ws + OFF_BOUT, ws + OFF_XZ, 128);
    for (int t = 0; t < TT; t++)
        lstm_step_kernel<32, false, true><<<BB * (LL / 16), 256, 0, stream>>>(
            ws + OFF_XZ, ws + OFF_WHOUT, (t & 1) ? hB : hA, (t & 1) ? hA : hB, cs,
            nullptr, dout, t);
}

// Round 5
// 1289.326 us; speedup vs baseline: 1.5343x; 1.5343x over previous
//
#include <hip/hip_runtime.h>
#include <hip/hip_bf16.h>

// ---------------------------------------------------------------------------
// PUSCH neural detector: 4 stacked ConvLSTM layers on [B=2,T=14,H=1536,W=1].
// 3x3 conv degenerates to width-3 conv along H (kw=1 slice). f32 throughout.
// Round 4: fast step kernel (global-coalesced w, vectorized LDS h-broadcast),
// vectorized GEMM inner loop, gate-interleaved xz columns.
// ---------------------------------------------------------------------------

#define BB   2
#define TT   14
#define LL   1536
#define CINR 297
#define CINP 304

// ---- workspace layout (units: f32 elements) -------------------------------
static constexpr size_t SZ_WXIN  = (size_t)3*CINP*256;
static constexpr size_t SZ_WH64  = (size_t)3*64*256;
static constexpr size_t SZ_WXOUT = (size_t)3*64*128;
static constexpr size_t SZ_WHOUT = (size_t)3*32*128;

static constexpr size_t OFF_WXIN  = 0;
static constexpr size_t OFF_WHIN  = OFF_WXIN  + SZ_WXIN;
static constexpr size_t OFF_WXR0  = OFF_WHIN  + SZ_WH64;
static constexpr size_t OFF_WHR0  = OFF_WXR0  + SZ_WH64;
static constexpr size_t OFF_WXR1  = OFF_WHR0  + SZ_WH64;
static constexpr size_t OFF_WHR1  = OFF_WXR1  + SZ_WH64;
static constexpr size_t OFF_WXOUT = OFF_WHR1  + SZ_WH64;
static constexpr size_t OFF_WHOUT = OFF_WXOUT + SZ_WXOUT;
static constexpr size_t OFF_BIN   = OFF_WHOUT + SZ_WHOUT;
static constexpr size_t OFF_BR0   = OFF_BIN + 256;
static constexpr size_t OFF_BR1   = OFF_BR0 + 256;
static constexpr size_t OFF_BOUT  = OFF_BR1 + 256;
static constexpr size_t PREP_TOTAL = OFF_BOUT + 128;

static constexpr size_t OFF_Z0  = 524288;                 // f32 [28][1536][304]
static constexpr size_t SZ_Z0   = (size_t)BB*TT*LL*CINP;
static constexpr size_t OFF_XZ  = OFF_Z0 + SZ_Z0;         // f32 [28][1536][256]
static constexpr size_t SZ_XZ   = (size_t)BB*TT*LL*256;
static constexpr size_t OFF_SEQ = OFF_XZ + SZ_XZ;         // f32 [28][1536][64]
static constexpr size_t SZ_SEQ  = (size_t)BB*TT*LL*64;
static constexpr size_t OFF_HA  = OFF_SEQ + SZ_SEQ;
static constexpr size_t SZ_HST  = (size_t)BB*LL*64;
static constexpr size_t OFF_HB  = OFF_HA + SZ_HST;
static constexpr size_t OFF_CS  = OFF_HB + SZ_HST;
// ~112 MB total

__device__ __forceinline__ float hsig(float x) {
    return fminf(fmaxf(0.2f * x + 0.5f, 0.0f), 1.0f);
}

// ---------------------------------------------------------------------------
// prep_weights.
// Wx stored [k][ci][co'] with co' = f*4+g (gate-interleaved columns) so the
// step epilogue reads the 4 gate pre-activations as one float4.
// Wh stored transposed [k][ci][f][gate4] (float4 per (ci,f)).
// Biases permuted to match co'.
// ---------------------------------------------------------------------------
__device__ __forceinline__ float wx_midP(const float* src, int Cin, int N, int idx) {
    int k = idx / (Cin * N); int r = idx - k * (Cin * N);
    int ci = r / N; int cop = r - ci * N;
    int Fo = N >> 2;
    int f = cop >> 2, g = cop & 3;
    return src[((size_t)(k * 3 + 1) * Cin + ci) * N + g * Fo + f];
}
__device__ __forceinline__ float wh_midT(const float* src, int F_, int idx) {
    int N4 = 4 * F_;
    int k = idx / (F_ * N4); int r = idx - k * (F_ * N4);
    int ci = r / N4; int fg = r - ci * N4;
    int f = fg >> 2, g = fg & 3;
    return src[((size_t)(k * 3 + 1) * F_ + ci) * N4 + g * F_ + f];
}

__global__ __launch_bounds__(256)
void prep_weights_kernel(const float* wx_in, const float* wh_in, const float* b_in,
                         const float* wx_r0, const float* wh_r0, const float* b_r0,
                         const float* wx_r1, const float* wh_r1, const float* b_r1,
                         const float* wx_out, const float* wh_out, const float* b_out,
                         float* __restrict__ ws)
{
    int idx = blockIdx.x * 256 + threadIdx.x;
    if (idx < (int)SZ_WXIN) {                      // Wx_in, ci padded 297->304
        int k = idx / (CINP * 256); int r = idx - k * (CINP * 256);
        int ci = r >> 8; int cop = r & 255;
        float v = 0.0f;
        if (ci < CINR) {
            int f = cop >> 2, g = cop & 3;
            v = wx_in[((size_t)(k * 3 + 1) * CINR + ci) * 256 + g * 64 + f];
        }
        ws[OFF_WXIN + idx] = v; return;
    }
    idx -= (int)SZ_WXIN;
    if (idx < (int)SZ_WH64) { ws[OFF_WHIN + idx] = wh_midT(wh_in, 64, idx); return; }
    idx -= (int)SZ_WH64;
    if (idx < (int)SZ_WH64) { ws[OFF_WXR0 + idx] = wx_midP(wx_r0, 64, 256, idx); return; }
    idx -= (int)SZ_WH64;
    if (idx < (int)SZ_WH64) { ws[OFF_WHR0 + idx] = wh_midT(wh_r0, 64, idx); return; }
    idx -= (int)SZ_WH64;
    if (idx < (int)SZ_WH64) { ws[OFF_WXR1 + idx] = wx_midP(wx_r1, 64, 256, idx); return; }
    idx -= (int)SZ_WH64;
    if (idx < (int)SZ_WH64) { ws[OFF_WHR1 + idx] = wh_midT(wh_r1, 64, idx); return; }
    idx -= (int)SZ_WH64;
    if (idx < (int)SZ_WXOUT) { ws[OFF_WXOUT + idx] = wx_midP(wx_out, 64, 128, idx); return; }
    idx -= (int)SZ_WXOUT;
    if (idx < (int)SZ_WHOUT) { ws[OFF_WHOUT + idx] = wh_midT(wh_out, 32, idx); return; }
    idx -= (int)SZ_WHOUT;
    if (idx < 256) { int f = idx >> 2, g = idx & 3; ws[OFF_BIN + idx] = b_in[g * 64 + f]; return; }
    idx -= 256;
    if (idx < 256) { int f = idx >> 2, g = idx & 3; ws[OFF_BR0 + idx] = b_r0[g * 64 + f]; return; }
    idx -= 256;
    if (idx < 256) { int f = idx >> 2, g = idx & 3; ws[OFF_BR1 + idx] = b_r1[g * 64 + f]; return; }
    idx -= 256;
    if (idx < 128) { int f = idx >> 2, g = idx & 3; ws[OFF_BOUT + idx] = b_out[g * 32 + f]; return; }
}

// ---------------------------------------------------------------------------
// build_features: gather [y | h | err | no] -> z0 f32 [28][1536][304]
// ---------------------------------------------------------------------------
__global__ __launch_bounds__(256)
void build_features_kernel(const float* __restrict__ y,
                           const float* __restrict__ h,
                           const float* __restrict__ ev,
                           const float* __restrict__ no,
                           float* __restrict__ z0)
{
    long long idx = (long long)blockIdx.x * 256 + threadIdx.x;
    const long long total = (long long)BB * TT * LL * CINP;
    if (idx >= total) return;
    int c = (int)(idx % CINP);
    long long rest = idx / CINP;
    int l = (int)(rest % LL); rest /= LL;
    int t = (int)(rest % TT);
    int b = (int)(rest / TT);
    float v = 0.0f;
    if (c < 32) {
        int na = c >> 1, ri = c & 1;
        v = y[((((long long)b * 16 + na) * TT + t) * LL + l) * 2 + ri];
    } else if (c < 288) {
        int q = c - 32;
        int ri = q & 1, nspu = (q >> 1) & 1, nue = (q >> 2) & 3, na = q >> 4;
        v = h[((((((long long)b * 16 + na) * 4 + nue) * 2 + nspu) * TT + t) * LL + l) * 2 + ri];
    } else if (c < 296) {
        int q = c - 288; int nspu = q & 1, nue = q >> 1;
        v = ev[(((long long)(nue * 2 + nspu) * TT + t) * LL) + l];
    } else if (c == 296) {
        v = no[0];
    }
    z0[idx] = v;
}

// ---------------------------------------------------------------------------
// xz_gemm v2: out[bt][l][co] = bias[co] + sum_{kh,ci} A[bt][l+kh-1][ci]*W[kh][ci][co]
// A-tile stored TRANSPOSED in LDS: As[kk][row] (pad 136) -> per kk one thread
// loads rows mbase..mbase+9 as b128/b64 and reuses them across the 3 conv taps.
// ---------------------------------------------------------------------------
__global__ __launch_bounds__(256)
void xz_gemm_kernel(const float* __restrict__ A, int CinPitch,
                    const float* __restrict__ Wg, const float* __restrict__ bias,
                    float* __restrict__ out, int Ncol)
{
    __shared__ float As[16 * 136];     // [c][row], rows 0..129 valid
    __shared__ float Ws[3 * 16 * 128];
    const int tid = threadIdx.x;
    const int bt = blockIdx.y;
    const int l0 = blockIdx.x * 128;
    const int n0 = blockIdx.z * 128;
    const int mbase = (tid >> 4) * 8;
    const int nbase = (tid & 15) * 8;

    float acc[8][8];
#pragma unroll
    for (int i = 0; i < 8; i++)
#pragma unroll
        for (int j = 0; j < 8; j++) acc[i][j] = 0.0f;

    for (int cc0 = 0; cc0 < CinPitch; cc0 += 16) {
        __syncthreads();
        // stage A rows l0-1 .. l0+128 (zero outside), 16 channels, transposed
        for (int idx = tid; idx < 130 * 16; idx += 256) {
            int r = idx >> 4, c = idx & 15;
            int row = l0 + r - 1;
            float v = 0.0f;
            if (row >= 0 && row < LL)
                v = A[((size_t)bt * LL + row) * CinPitch + cc0 + c];
            As[c * 136 + r] = v;
        }
        // stage W [3][16][128] with float4
        for (int i4 = tid; i4 < 3 * 16 * 32; i4 += 256) {
            int kh = i4 >> 9;
            int r2 = i4 & 511;
            int kk = r2 >> 5, n4 = r2 & 31;
            float4 w = *reinterpret_cast<const float4*>(
                &Wg[((size_t)kh * CinPitch + cc0 + kk) * Ncol + n0 + n4 * 4]);
            *reinterpret_cast<float4*>(&Ws[(kh * 16 + kk) * 128 + n4 * 4]) = w;
        }
        __syncthreads();
        for (int kk = 0; kk < 16; ++kk) {
            float a[10];
            *reinterpret_cast<float4*>(&a[0]) =
                *reinterpret_cast<const float4*>(&As[kk * 136 + mbase]);
            *reinterpret_cast<float4*>(&a[4]) =
                *reinterpret_cast<const float4*>(&As[kk * 136 + mbase + 4]);
            *reinterpret_cast<float2*>(&a[8]) =
                *reinterpret_cast<const float2*>(&As[kk * 136 + mbase + 8]);
#pragma unroll
            for (int kh = 0; kh < 3; ++kh) {
                float w[8];
                *reinterpret_cast<float4*>(&w[0]) =
                    *reinterpret_cast<const float4*>(&Ws[(kh * 16 + kk) * 128 + nbase]);
                *reinterpret_cast<float4*>(&w[4]) =
                    *reinterpret_cast<const float4*>(&Ws[(kh * 16 + kk) * 128 + nbase + 4]);
#pragma unroll
                for (int i = 0; i < 8; i++)
#pragma unroll
                    for (int j = 0; j < 8; j++)
                        acc[i][j] = fmaf(a[i + kh], w[j], acc[i][j]);
            }
        }
    }
#pragma unroll
    for (int i = 0; i < 8; i++) {
        int row = l0 + mbase + i;
        float* orow = out + ((size_t)bt * LL + row) * Ncol + n0 + nbase;
        float4 o0, o1;
        o0.x = acc[i][0] + bias[n0 + nbase + 0];
        o0.y = acc[i][1] + bias[n0 + nbase + 1];
        o0.z = acc[i][2] + bias[n0 + nbase + 2];
        o0.w = acc[i][3] + bias[n0 + nbase + 3];
        o1.x = acc[i][4] + bias[n0 + nbase + 4];
        o1.y = acc[i][5] + bias[n0 + nbase + 5];
        o1.z = acc[i][6] + bias[n0 + nbase + 6];
        o1.w = acc[i][7] + bias[n0 + nbase + 7];
        *reinterpret_cast<float4*>(orow) = o0;
        *reinterpret_cast<float4*>(orow + 4) = o1;
    }
}

// ---------------------------------------------------------------------------
// lstm_step v2: z = xz[t] + conv3(h_prev, Wh); gates; update c,h.
// Weights read directly from global as float4 (coalesced, L1/L2-resident);
// h_prev staged in LDS with halo, read as wave-uniform float4 broadcasts.
// One barrier per step. h double-buffered across launches (halo race).
// ---------------------------------------------------------------------------
template <int F_, bool RESID, bool OUTW>
__global__ __launch_bounds__(256)
void lstm_step_kernel(const float* __restrict__ xz,      // [28][1536][F_*4] gate-interleaved
                      const float4* __restrict__ Wh4,    // [3][F_][F_] float4 (i,f,g,o)
                      const float* __restrict__ hprev,   // [B][1536][F_]
                      float* __restrict__ hnext,
                      float* __restrict__ cstate,
                      float* seq,                        // layer in/out seq (or null)
                      float* __restrict__ dout,          // final output f32 (or null)
                      int t)
{
    constexpr int ROWS = 16;
    constexpr int RG = 256 / F_;        // 4 (F=64) / 8 (F=32)
    constexpr int R = ROWS / RG;        // 4 / 2
    __shared__ float Hs[(ROWS + 2) * F_];

    const int tid = threadIdx.x;
    const int f = tid % F_;
    const int rg = tid / F_;
    const int nLb = LL / ROWS;          // 96
    const int b = blockIdx.x / nLb;
    const int l0 = (blockIdx.x % nLb) * ROWS;
    const int rgR = rg * R;

    // stage h_prev rows l0-1 .. l0+16 (zeros at t==0 / edges)
    for (int idx = tid; idx < (ROWS + 2) * F_; idx += 256) {
        int r = idx / F_, c = idx % F_;
        int row = l0 + r - 1;
        float v = 0.0f;
        if (t > 0 && row >= 0 && row < LL) v = hprev[((size_t)b * LL + row) * F_ + c];
        Hs[idx] = v;
    }
    __syncthreads();

    float4 zh[R];
#pragma unroll
    for (int i = 0; i < R; i++) zh[i] = make_float4(0.f, 0.f, 0.f, 0.f);

    if (t > 0) {
#pragma unroll
        for (int k = 0; k < 3; k++) {
            const float4* __restrict__ wk = Wh4 + (size_t)k * F_ * F_;
            const float* __restrict__ hk = &Hs[(rgR + k) * F_];
#pragma unroll 2
            for (int c4 = 0; c4 < F_; c4 += 4) {
                float4 w0 = wk[(c4 + 0) * F_ + f];
                float4 w1 = wk[(c4 + 1) * F_ + f];
                float4 w2 = wk[(c4 + 2) * F_ + f];
                float4 w3 = wk[(c4 + 3) * F_ + f];
#pragma unroll
                for (int i = 0; i < R; i++) {
                    const float4 h4 = *reinterpret_cast<const float4*>(&hk[i * F_ + c4]);
                    zh[i].x = fmaf(h4.x, w0.x, zh[i].x);
                    zh[i].y = fmaf(h4.x, w0.y, zh[i].y);
                    zh[i].z = fmaf(h4.x, w0.z, zh[i].z);
                    zh[i].w = fmaf(h4.x, w0.w, zh[i].w);
                    zh[i].x = fmaf(h4.y, w1.x, zh[i].x);
                    zh[i].y = fmaf(h4.y, w1.y, zh[i].y);
                    zh[i].z = fmaf(h4.y, w1.z, zh[i].z);
                    zh[i].w = fmaf(h4.y, w1.w, zh[i].w);
                    zh[i].x = fmaf(h4.z, w2.x, zh[i].x);
                    zh[i].y = fmaf(h4.z, w2.y, zh[i].y);
                    zh[i].z = fmaf(h4.z, w2.z, zh[i].z);
                    zh[i].w = fmaf(h4.z, w2.w, zh[i].w);
                    zh[i].x = fmaf(h4.w, w3.x, zh[i].x);
                    zh[i].y = fmaf(h4.w, w3.y, zh[i].y);
                    zh[i].z = fmaf(h4.w, w3.z, zh[i].z);
                    zh[i].w = fmaf(h4.w, w3.w, zh[i].w);
                }
            }
        }
    }

    const size_t btL = ((size_t)b * TT + t) * LL;
#pragma unroll
    for (int i = 0; i < R; i++) {
        int l = l0 + rgR + i;
        const float4 z4 = *reinterpret_cast<const float4*>(
            &xz[(btL + l) * (size_t)(4 * F_) + f * 4]);
        float zi = z4.x + zh[i].x;
        float zf = z4.y + zh[i].y;
        float zg = z4.z + zh[i].z;
        float zo = z4.w + zh[i].w;
        float ig = hsig(zi), fg = hsig(zf);
        float gg = tanhf(zg), og = hsig(zo);
        size_t soff = ((size_t)b * LL + l) * F_ + f;
        float cp = (t > 0) ? cstate[soff] : 0.0f;
        float cn = fg * cp + ig * gg;
        float hn = og * tanhf(cn);
        cstate[soff] = cn;
        hnext[soff] = hn;
        if (OUTW) {
            // out[b][ue][spu][n*4+bit]; f = ue*8 + spu*4 + bit; n = t*L + l
            int ue = f >> 3, spu = (f >> 2) & 1, bit = f & 3;
            size_t n = (size_t)t * LL + l;
            dout[(((size_t)b * 4 + ue) * 2 + spu) * ((size_t)TT * LL * 4) + n * 4 + bit] = hn;
        } else {
            float v = hn;
            if (RESID) v += seq[(btL + l) * F_ + f];   // same idx, same thread
            seq[(btL + l) * F_ + f] = v;
        }
    }
}

// ---------------------------------------------------------------------------
extern "C" void kernel_launch(void* const* d_in, const int* in_sizes, int n_in,
                              void* d_out, int out_size, void* d_ws, size_t ws_size,
                              hipStream_t stream)
{
    (void)in_sizes; (void)n_in; (void)out_size; (void)ws_size;
    const float* y_ri   = (const float*)d_in[0];
    const float* h_ri   = (const float*)d_in[1];
    const float* evar   = (const float*)d_in[2];
    const float* no     = (const float*)d_in[3];
    const float* wx_in  = (const float*)d_in[4];
    const float* wh_in  = (const float*)d_in[5];
    const float* b_in   = (const float*)d_in[6];
    const float* wx_r0  = (const float*)d_in[7];
    const float* wh_r0  = (const float*)d_in[8];
    const float* b_r0   = (const float*)d_in[9];
    const float* wx_r1  = (const float*)d_in[10];
    const float* wh_r1  = (const float*)d_in[11];
    const float* b_r1   = (const float*)d_in[12];
    const float* wx_out = (const float*)d_in[13];
    const float* wh_out = (const float*)d_in[14];
    const float* b_out  = (const float*)d_in[15];

    float* ws = (float*)d_ws;
    float* dout = (float*)d_out;

    {
        int blocks = (int)((PREP_TOTAL + 255) / 256);
        prep_weights_kernel<<<blocks, 256, 0, stream>>>(
            wx_in, wh_in, b_in, wx_r0, wh_r0, b_r0,
            wx_r1, wh_r1, b_r1, wx_out, wh_out, b_out, ws);
    }
    {
        long long total = (long long)BB * TT * LL * CINP;
        int blocks = (int)((total + 255) / 256);
        build_features_kernel<<<blocks, 256, 0, stream>>>(
            y_ri, h_ri, evar, no, ws + OFF_Z0);
    }

    float* hA = ws + OFF_HA;
    float* hB = ws + OFF_HB;
    float* cs = ws + OFF_CS;
    float* seq = ws + OFF_SEQ;
    const dim3 g256(12, BB * TT, 2);
    const dim3 g128(12, BB * TT, 1);
    const int stepGrid = BB * (LL / 16);     // 192

    // ---- layer in: Cin=297(p304) -> F=64
    xz_gemm_kernel<<<g256, 256, 0, stream>>>(
        ws + OFF_Z0, CINP, ws + OFF_WXIN, ws + OFF_BIN, ws + OFF_XZ, 256);
    for (int t = 0; t < TT; t++)
        lstm_step_kernel<64, false, false><<<stepGrid, 256, 0, stream>>>(
            ws + OFF_XZ, (const float4*)(ws + OFF_WHIN),
            (t & 1) ? hB : hA, (t & 1) ? hA : hB, cs, seq, nullptr, t);

    // ---- layer r0 (+residual, in-place on seq)
    xz_gemm_kernel<<<g256, 256, 0, stream>>>(
        seq, 64, ws + OFF_WXR0, ws + OFF_BR0, ws + OFF_XZ, 256);
    for (int t = 0; t < TT; t++)
        lstm_step_kernel<64, true, false><<<stepGrid, 256, 0, stream>>>(
            ws + OFF_XZ, (const float4*)(ws + OFF_WHR0),
            (t & 1) ? hB : hA, (t & 1) ? hA : hB, cs, seq, nullptr, t);

    // ---- layer r1 (+residual, in-place on seq)
    xz_gemm_kernel<<<g256, 256, 0, stream>>>(
        seq, 64, ws + OFF_WXR1, ws + OFF_BR1, ws + OFF_XZ, 256);
    for (int t = 0; t < TT; t++)
        lstm_step_kernel<64, true, false><<<stepGrid, 256, 0, stream>>>(
            ws + OFF_XZ, (const float4*)(ws + OFF_WHR1),
            (t & 1) ? hB : hA, (t & 1) ? hA : hB, cs, seq, nullptr, t);

    // ---- layer out: F=32, writes d_out (f32, transposed layout)
    xz_gemm_kernel<<<g128, 256, 0, stream>>>(
        seq, 64, ws + OFF_WXOUT, ws + OFF_BOUT, ws + OFF_XZ, 128);
    for (int t = 0; t < TT; t++)
        lstm_step_kernel<32, false, true><<<stepGrid, 256, 0, stream>>>(
            ws + OFF_XZ, (const float4*)(ws + OFF_WHOUT),
            (t & 1) ? hB : hA, (t & 1) ? hA : hB, cs, nullptr, dout, t);
}